// Round 5
// baseline (481.510 us; speedup 1.0000x reference)
//
#include <hip/hip_runtime.h>

#define N_NODES 100000
#define N_EDGES 1200000
#define D 64
#define KEEP_PROB 0.7f
#define INV_KEEP (1.0f / KEEP_PROB)
#define NB_SCAN 196   // ceil(N_NODES/512)

#define ALOAD_I(p)   __hip_atomic_load((p), __ATOMIC_RELAXED, __HIP_MEMORY_SCOPE_AGENT)
#define ALOAD_U64(p) __hip_atomic_load((p), __ATOMIC_RELAXED, __HIP_MEMORY_SCOPE_AGENT)

// ---------------------------------------------------------------------------
__global__ __launch_bounds__(256) void zero_kernel(float4* __restrict__ p, int n4) {
    int i = blockIdx.x * 256 + threadIdx.x;
    if (i < n4) p[i] = make_float4(0.f, 0.f, 0.f, 0.f);
}

// ---------------------------------------------------------------------------
// CSR build 1: per-row counts
__global__ __launch_bounds__(256) void hist_kernel(const int* __restrict__ rows,
                                                   int* __restrict__ cnt) {
    int e = blockIdx.x * 256 + threadIdx.x;
    if (e < N_EDGES) atomicAdd(&cnt[rows[e]], 1);
}

// ---------------------------------------------------------------------------
// CSR build 2a: per-512-chunk sums of cnt
__global__ __launch_bounds__(256) void blocksum_kernel(const int* __restrict__ cnt,
                                                       int* __restrict__ bsum) {
    __shared__ int red[256];
    int t = threadIdx.x;
    int base = blockIdx.x * 512;
    int i0 = base + t, i1 = base + 256 + t;
    int s = 0;
    if (i0 < N_NODES) s += ALOAD_I(&cnt[i0]);
    if (i1 < N_NODES) s += ALOAD_I(&cnt[i1]);
    red[t] = s;
    __syncthreads();
    for (int d = 128; d > 0; d >>= 1) {
        if (t < d) red[t] += red[t + d];
        __syncthreads();
    }
    if (t == 0) bsum[blockIdx.x] = red[0];
}

// ---------------------------------------------------------------------------
// CSR build 2b: exclusive scan of 196 block sums (in place); sentinel
__global__ __launch_bounds__(256) void bscan_kernel(int* __restrict__ bsum,
                                                    int* __restrict__ Pstart) {
    __shared__ int part[256];
    int t = threadIdx.x;
    int v = (t < NB_SCAN) ? bsum[t] : 0;
    part[t] = v;
    __syncthreads();
    for (int d = 1; d < 256; d <<= 1) {
        int w = (t >= d) ? part[t - d] : 0;
        __syncthreads();
        part[t] += w;
        __syncthreads();
    }
    if (t < NB_SCAN) bsum[t] = part[t] - v;
    if (t == 0) Pstart[N_NODES] = N_EDGES;
}

// ---------------------------------------------------------------------------
// CSR build 2c: block-local exclusive scan + block offset -> Pstart, cursor
__global__ __launch_bounds__(256) void scan2_kernel(const int* __restrict__ cnt,
                                                    const int* __restrict__ bofs,
                                                    int* __restrict__ Pstart,
                                                    int* __restrict__ cursor) {
    __shared__ int part[256];
    int t = threadIdx.x;
    int base = blockIdx.x * 512;
    int i0 = base + 2 * t, i1 = i0 + 1;
    int e0 = (i0 < N_NODES) ? ALOAD_I(&cnt[i0]) : 0;
    int e1 = (i1 < N_NODES) ? ALOAD_I(&cnt[i1]) : 0;
    int s = e0 + e1;
    part[t] = s;
    __syncthreads();
    for (int d = 1; d < 256; d <<= 1) {
        int w = (t >= d) ? part[t - d] : 0;
        __syncthreads();
        part[t] += w;
        __syncthreads();
    }
    int pref = bofs[blockIdx.x] + part[t] - s;
    if (i0 < N_NODES) { Pstart[i0] = pref;      cursor[i0] = pref; }
    if (i1 < N_NODES) { Pstart[i1] = pref + e0; cursor[i1] = pref + e0; }
}

// ---------------------------------------------------------------------------
// CSR build 3: scatter edges row-grouped; ONE 16B record per edge:
// (col, v0, col, v1) so each layer reads a contiguous 8B {col, vL} pair.
// Single uint4 store -> 1 cache line dirtied per edge (vs 3 in R4).
__global__ __launch_bounds__(256) void scatter_kernel(
    const int*   __restrict__ rows,
    const int*   __restrict__ cols,
    const float* __restrict__ vals,
    const float* __restrict__ drop_u,   // [2, E]
    int*         __restrict__ cursor,
    uint4*       __restrict__ edata) {
    int e = blockIdx.x * 256 + threadIdx.x;
    if (e >= N_EDGES) return;
    int r = rows[e];
    int pos = atomicAdd(&cursor[r], 1);
    unsigned c = (unsigned)cols[e];
    float v = vals[e] * INV_KEEP;
    float v0 = (drop_u[e] + KEEP_PROB >= 1.0f) ? v : 0.f;
    float v1 = (drop_u[N_EDGES + e] + KEEP_PROB >= 1.0f) ? v : 0.f;
    uint4 rec;
    rec.x = c; rec.y = __float_as_uint(v0);
    rec.z = c; rec.w = __float_as_uint(v1);
    edata[pos] = rec;
}

// ---------------------------------------------------------------------------
// Gather SpMM: one wave per row, one lane per feature.
// Per edge: one 8B agent-scope load of {col, vL}; skip gather when vL==0
// (wave-uniform -> masked load issues no memory requests).
// layer 0: io[row] = acc ; layer 1: io[row] = (io[row] + acc) / 3
__global__ __launch_bounds__(256) void spmm_gather_kernel(
    const float* __restrict__ x_in,
    const unsigned long long* __restrict__ edata,  // 2 u64 per edge
    const int*   __restrict__ Pstart,
    float*       __restrict__ io,
    int layer) {
    int wave = (blockIdx.x * 256 + threadIdx.x) >> 6;
    int lane = threadIdx.x & 63;
    if (wave >= N_NODES) return;
    int start = ALOAD_I(&Pstart[wave]);
    int end   = ALOAD_I(&Pstart[wave + 1]);
    float acc = 0.f;
    #pragma unroll 4
    for (int i = start; i < end; ++i) {
        unsigned long long rec = ALOAD_U64(&edata[2 * i + layer]);
        int   c = (int)(rec & 0xffffffffu);
        float v = __uint_as_float((unsigned)(rec >> 32));
        if (v != 0.f)
            acc = fmaf(v, x_in[(c << 6) + lane], acc);
    }
    int o = (wave << 6) + lane;
    if (layer == 0) io[o] = acc;
    else            io[o] = (io[o] + acc) * (1.0f / 3.0f);
}

// ---------------------------------------------------------------------------
// out[n,j] = b[j] + sum_k emb[n,k]*W[j,k] + x1[n,j]
__global__ __launch_bounds__(256) void fc_add_kernel(
    const float* __restrict__ emb,
    const float* __restrict__ W,
    const float* __restrict__ b,
    const float* __restrict__ x1,
    float*       __restrict__ out) {
    __shared__ float Ws[D * 65];
    __shared__ float Es[4 * D];

    int t = threadIdx.x;
    #pragma unroll
    for (int i = 0; i < 16; ++i) {
        int idx = i * 256 + t;
        Ws[(idx >> 6) * 65 + (idx & 63)] = W[idx];
    }
    int node0 = blockIdx.x * 4;
    Es[t] = emb[node0 * D + t];
    __syncthreads();

    int local = t >> 6;
    int j     = t & 63;
    int n     = node0 + local;

    float acc = b[j];
    const float* es = &Es[local * D];
    const float* ws = &Ws[j * 65];
    #pragma unroll
    for (int k = 0; k < D; ++k) acc += es[k] * ws[k];
    out[n * D + j] = acc + x1[n * D + j];
}

// ---------------------------------------------------------------------------
// Fallback (atomic path, replay-proven) if ws too small
__global__ __launch_bounds__(256) void spmm_atomic_kernel(
    const float* __restrict__ x_in,
    const float* __restrict__ vals,
    const float* __restrict__ drop_u,
    const int*   __restrict__ rows,
    const int*   __restrict__ cols,
    float*       __restrict__ x_out) {
    int wave = (blockIdx.x * 256 + threadIdx.x) >> 6;
    int lane = threadIdx.x & 63;
    if (wave >= N_EDGES) return;
    float u = drop_u[wave];
    if (u + KEEP_PROB < 1.0f) return;
    float v = vals[wave] * INV_KEEP;
    atomicAdd(&x_out[rows[wave] * D + lane], v * x_in[cols[wave] * D + lane]);
}

__global__ __launch_bounds__(256) void scale_kernel(float4* __restrict__ p, int n4) {
    int i = blockIdx.x * 256 + threadIdx.x;
    if (i < n4) {
        float4 v = p[i];
        v.x *= (1.f/3.f); v.y *= (1.f/3.f); v.z *= (1.f/3.f); v.w *= (1.f/3.f);
        p[i] = v;
    }
}

// ---------------------------------------------------------------------------
extern "C" void kernel_launch(void* const* d_in, const int* in_sizes, int n_in,
                              void* d_out, int out_size, void* d_ws, size_t ws_size,
                              hipStream_t stream) {
    const float* all_emb = (const float*)d_in[0];
    const float* W       = (const float*)d_in[1];
    const float* b       = (const float*)d_in[2];
    const float* vals    = (const float*)d_in[3];
    const float* drop_u  = (const float*)d_in[4];   // [2, E]
    const int*   rows    = (const int*)d_in[5];
    const int*   cols    = (const int*)d_in[6];

    float* out = (float*)d_out;

    // workspace layout (16B aligned)
    char* ws = (char*)d_ws;
    float* x1     = (float*)(ws);                   // 25,600,000 B
    int*   Pstart = (int*)  (ws + 25600000);        //    400,064 B (N+1 ints, padded)
    int*   cnt    = (int*)  (ws + 26000064);        //    400,000 B (counts -> cursor)
    uint4* edata  = (uint4*)(ws + 26400064);        // 19,200,000 B (E x 16B records)
    int*   bsum   = (int*)  (ws + 45600064);        //      1,024 B
    const size_t WS_NEEDED = 45601088;

    const int n4 = N_NODES * D / 4;
    const int zb = (n4 + 255) / 256;
    const int edge_blocks = (N_EDGES + 255) / 256;     // 4688
    const int row_wave_blocks = (N_NODES + 3) / 4;     // 25000

    if (ws_size >= WS_NEEDED) {
        zero_kernel<<<(N_NODES/4 + 255)/256, 256, 0, stream>>>((float4*)cnt, N_NODES/4);
        hist_kernel<<<edge_blocks, 256, 0, stream>>>(rows, cnt);
        blocksum_kernel<<<NB_SCAN, 256, 0, stream>>>(cnt, bsum);
        bscan_kernel<<<1, 256, 0, stream>>>(bsum, Pstart);
        scan2_kernel<<<NB_SCAN, 256, 0, stream>>>(cnt, bsum, Pstart, cnt);
        scatter_kernel<<<edge_blocks, 256, 0, stream>>>(rows, cols, vals, drop_u,
                                                        cnt, edata);
        // layer 0: x1 = A1 @ all_emb
        spmm_gather_kernel<<<row_wave_blocks, 256, 0, stream>>>(
            all_emb, (const unsigned long long*)edata, Pstart, x1, 0);
        // out = fc(all_emb) + x1
        fc_add_kernel<<<N_NODES / 4, 256, 0, stream>>>(all_emb, W, b, x1, out);
        // layer 1 (fused /3): out = (out + A2 @ x1) / 3
        spmm_gather_kernel<<<row_wave_blocks, 256, 0, stream>>>(
            x1, (const unsigned long long*)edata, Pstart, out, 1);
    } else {
        // fallback: proven atomic path
        const int spmm_blocks = (N_EDGES + 3) / 4;
        zero_kernel<<<zb, 256, 0, stream>>>((float4*)x1, n4);
        spmm_atomic_kernel<<<spmm_blocks, 256, 0, stream>>>(all_emb, vals, drop_u,
                                                            rows, cols, x1);
        fc_add_kernel<<<N_NODES / 4, 256, 0, stream>>>(all_emb, W, b, x1, out);
        spmm_atomic_kernel<<<spmm_blocks, 256, 0, stream>>>(x1, vals,
                                                            drop_u + N_EDGES,
                                                            rows, cols, out);
        scale_kernel<<<zb, 256, 0, stream>>>((float4*)out, n4);
    }
}

// Round 6
// 379.430 us; speedup vs baseline: 1.2690x; 1.2690x over previous
//
#include <hip/hip_runtime.h>

#define N_NODES 100000
#define N_EDGES 1200000
#define D 64
#define KEEP_PROB 0.7f
#define INV_KEEP (1.0f / KEEP_PROB)
#define NB_SCAN 196   // ceil(N_NODES/512)

#define ALOAD_I(p)   __hip_atomic_load((p), __ATOMIC_RELAXED, __HIP_MEMORY_SCOPE_AGENT)
#define ALOAD_U64(p) __hip_atomic_load((p), __ATOMIC_RELAXED, __HIP_MEMORY_SCOPE_AGENT)

// ---------------------------------------------------------------------------
__global__ __launch_bounds__(256) void zero_kernel(float4* __restrict__ p, int n4) {
    int i = blockIdx.x * 256 + threadIdx.x;
    if (i < n4) p[i] = make_float4(0.f, 0.f, 0.f, 0.f);
}

// ---------------------------------------------------------------------------
// CSR build 1: per-row counts
__global__ __launch_bounds__(256) void hist_kernel(const int* __restrict__ rows,
                                                   int* __restrict__ cnt) {
    int e = blockIdx.x * 256 + threadIdx.x;
    if (e < N_EDGES) atomicAdd(&cnt[rows[e]], 1);
}

// ---------------------------------------------------------------------------
// CSR build 2a: per-512-chunk sums of cnt
__global__ __launch_bounds__(256) void blocksum_kernel(const int* __restrict__ cnt,
                                                       int* __restrict__ bsum) {
    __shared__ int red[256];
    int t = threadIdx.x;
    int base = blockIdx.x * 512;
    int i0 = base + t, i1 = base + 256 + t;
    int s = 0;
    if (i0 < N_NODES) s += ALOAD_I(&cnt[i0]);
    if (i1 < N_NODES) s += ALOAD_I(&cnt[i1]);
    red[t] = s;
    __syncthreads();
    for (int d = 128; d > 0; d >>= 1) {
        if (t < d) red[t] += red[t + d];
        __syncthreads();
    }
    if (t == 0) bsum[blockIdx.x] = red[0];
}

// ---------------------------------------------------------------------------
// CSR build 2b: exclusive scan of 196 block sums (in place); sentinel
__global__ __launch_bounds__(256) void bscan_kernel(int* __restrict__ bsum,
                                                    int* __restrict__ Pstart) {
    __shared__ int part[256];
    int t = threadIdx.x;
    int v = (t < NB_SCAN) ? bsum[t] : 0;
    part[t] = v;
    __syncthreads();
    for (int d = 1; d < 256; d <<= 1) {
        int w = (t >= d) ? part[t - d] : 0;
        __syncthreads();
        part[t] += w;
        __syncthreads();
    }
    if (t < NB_SCAN) bsum[t] = part[t] - v;
    if (t == 0) Pstart[N_NODES] = N_EDGES;
}

// ---------------------------------------------------------------------------
// CSR build 2c: block-local exclusive scan + block offset -> Pstart, cursor
__global__ __launch_bounds__(256) void scan2_kernel(const int* __restrict__ cnt,
                                                    const int* __restrict__ bofs,
                                                    int* __restrict__ Pstart,
                                                    int* __restrict__ cursor) {
    __shared__ int part[256];
    int t = threadIdx.x;
    int base = blockIdx.x * 512;
    int i0 = base + 2 * t, i1 = i0 + 1;
    int e0 = (i0 < N_NODES) ? ALOAD_I(&cnt[i0]) : 0;
    int e1 = (i1 < N_NODES) ? ALOAD_I(&cnt[i1]) : 0;
    int s = e0 + e1;
    part[t] = s;
    __syncthreads();
    for (int d = 1; d < 256; d <<= 1) {
        int w = (t >= d) ? part[t - d] : 0;
        __syncthreads();
        part[t] += w;
        __syncthreads();
    }
    int pref = bofs[blockIdx.x] + part[t] - s;
    if (i0 < N_NODES) { Pstart[i0] = pref;      cursor[i0] = pref; }
    if (i1 < N_NODES) { Pstart[i1] = pref + e0; cursor[i1] = pref + e0; }
}

// ---------------------------------------------------------------------------
// CSR build 3: scatter edges row-grouped; ONE 16B record per edge:
// (col, v0, col, v1). Single uint4 store -> 1 line dirtied per edge.
__global__ __launch_bounds__(256) void scatter_kernel(
    const int*   __restrict__ rows,
    const int*   __restrict__ cols,
    const float* __restrict__ vals,
    const float* __restrict__ drop_u,   // [2, E]
    int*         __restrict__ cursor,
    uint4*       __restrict__ edata) {
    int e = blockIdx.x * 256 + threadIdx.x;
    if (e >= N_EDGES) return;
    int r = rows[e];
    int pos = atomicAdd(&cursor[r], 1);
    unsigned c = (unsigned)cols[e];
    float v = vals[e] * INV_KEEP;
    float v0 = (drop_u[e] + KEEP_PROB >= 1.0f) ? v : 0.f;
    float v1 = (drop_u[N_EDGES + e] + KEEP_PROB >= 1.0f) ? v : 0.f;
    uint4 rec;
    rec.x = c; rec.y = __float_as_uint(v0);
    rec.z = c; rec.w = __float_as_uint(v1);
    edata[pos] = rec;
}

// ---------------------------------------------------------------------------
// Gather SpMM: 16 lanes per row (float4/lane), 4 independent rows per wave.
// Branch-free + unroll 4 -> up to 16 outstanding gathers per wave (MLP).
// layer 0: io[row] = acc ; layer 1: io[row] = (io[row] + acc) / 3
__global__ __launch_bounds__(256) void spmm_gather_kernel(
    const float4* __restrict__ x_in,               // node rows = 16 float4
    const unsigned long long* __restrict__ edata,  // 2 u64 per edge
    const int*   __restrict__ Pstart,
    float4*      __restrict__ io,
    int layer) {
    int tid = blockIdx.x * 256 + threadIdx.x;
    int row = tid >> 4;              // 16 threads per row
    int l16 = threadIdx.x & 15;
    if (row >= N_NODES) return;
    int start = ALOAD_I(&Pstart[row]);
    int end   = ALOAD_I(&Pstart[row + 1]);
    float4 acc = make_float4(0.f, 0.f, 0.f, 0.f);
    #pragma unroll 4
    for (int i = start; i < end; ++i) {
        unsigned long long rec = ALOAD_U64(&edata[2 * i + layer]);
        int   c = (int)(rec & 0xffffffffu);
        float v = __uint_as_float((unsigned)(rec >> 32));
        float4 x = x_in[(c << 4) + l16];
        acc.x = fmaf(v, x.x, acc.x);
        acc.y = fmaf(v, x.y, acc.y);
        acc.z = fmaf(v, x.z, acc.z);
        acc.w = fmaf(v, x.w, acc.w);
    }
    int o = (row << 4) + l16;
    if (layer == 0) {
        io[o] = acc;
    } else {
        float4 p = io[o];
        p.x = (p.x + acc.x) * (1.0f / 3.0f);
        p.y = (p.y + acc.y) * (1.0f / 3.0f);
        p.z = (p.z + acc.z) * (1.0f / 3.0f);
        p.w = (p.w + acc.w) * (1.0f / 3.0f);
        io[o] = p;
    }
}

// ---------------------------------------------------------------------------
// out[n,j] = b[j] + sum_k emb[n,k]*W[j,k] + x1[n,j]
__global__ __launch_bounds__(256) void fc_add_kernel(
    const float* __restrict__ emb,
    const float* __restrict__ W,
    const float* __restrict__ b,
    const float* __restrict__ x1,
    float*       __restrict__ out) {
    __shared__ float Ws[D * 65];
    __shared__ float Es[4 * D];

    int t = threadIdx.x;
    #pragma unroll
    for (int i = 0; i < 16; ++i) {
        int idx = i * 256 + t;
        Ws[(idx >> 6) * 65 + (idx & 63)] = W[idx];
    }
    int node0 = blockIdx.x * 4;
    Es[t] = emb[node0 * D + t];
    __syncthreads();

    int local = t >> 6;
    int j     = t & 63;
    int n     = node0 + local;

    float acc = b[j];
    const float* es = &Es[local * D];
    const float* ws = &Ws[j * 65];
    #pragma unroll
    for (int k = 0; k < D; ++k) acc += es[k] * ws[k];
    out[n * D + j] = acc + x1[n * D + j];
}

// ---------------------------------------------------------------------------
// Fallback (atomic path, replay-proven) if ws too small
__global__ __launch_bounds__(256) void spmm_atomic_kernel(
    const float* __restrict__ x_in,
    const float* __restrict__ vals,
    const float* __restrict__ drop_u,
    const int*   __restrict__ rows,
    const int*   __restrict__ cols,
    float*       __restrict__ x_out) {
    int wave = (blockIdx.x * 256 + threadIdx.x) >> 6;
    int lane = threadIdx.x & 63;
    if (wave >= N_EDGES) return;
    float u = drop_u[wave];
    if (u + KEEP_PROB < 1.0f) return;
    float v = vals[wave] * INV_KEEP;
    atomicAdd(&x_out[rows[wave] * D + lane], v * x_in[cols[wave] * D + lane]);
}

__global__ __launch_bounds__(256) void scale_kernel(float4* __restrict__ p, int n4) {
    int i = blockIdx.x * 256 + threadIdx.x;
    if (i < n4) {
        float4 v = p[i];
        v.x *= (1.f/3.f); v.y *= (1.f/3.f); v.z *= (1.f/3.f); v.w *= (1.f/3.f);
        p[i] = v;
    }
}

// ---------------------------------------------------------------------------
extern "C" void kernel_launch(void* const* d_in, const int* in_sizes, int n_in,
                              void* d_out, int out_size, void* d_ws, size_t ws_size,
                              hipStream_t stream) {
    const float* all_emb = (const float*)d_in[0];
    const float* W       = (const float*)d_in[1];
    const float* b       = (const float*)d_in[2];
    const float* vals    = (const float*)d_in[3];
    const float* drop_u  = (const float*)d_in[4];   // [2, E]
    const int*   rows    = (const int*)d_in[5];
    const int*   cols    = (const int*)d_in[6];

    float* out = (float*)d_out;

    // workspace layout (16B aligned)
    char* ws = (char*)d_ws;
    float* x1     = (float*)(ws);                   // 25,600,000 B
    int*   Pstart = (int*)  (ws + 25600000);        //    400,064 B
    int*   cnt    = (int*)  (ws + 26000064);        //    400,000 B (counts -> cursor)
    uint4* edata  = (uint4*)(ws + 26400064);        // 19,200,000 B (E x 16B)
    int*   bsum   = (int*)  (ws + 45600064);        //      1,024 B
    const size_t WS_NEEDED = 45601088;

    const int n4 = N_NODES * D / 4;
    const int zb = (n4 + 255) / 256;
    const int edge_blocks = (N_EDGES + 255) / 256;       // 4688
    const int gather_blocks = (N_NODES * 16 + 255) / 256; // 6250 (16 thr/row)

    if (ws_size >= WS_NEEDED) {
        zero_kernel<<<(N_NODES/4 + 255)/256, 256, 0, stream>>>((float4*)cnt, N_NODES/4);
        hist_kernel<<<edge_blocks, 256, 0, stream>>>(rows, cnt);
        blocksum_kernel<<<NB_SCAN, 256, 0, stream>>>(cnt, bsum);
        bscan_kernel<<<1, 256, 0, stream>>>(bsum, Pstart);
        scan2_kernel<<<NB_SCAN, 256, 0, stream>>>(cnt, bsum, Pstart, cnt);
        scatter_kernel<<<edge_blocks, 256, 0, stream>>>(rows, cols, vals, drop_u,
                                                        cnt, edata);
        // layer 0: x1 = A1 @ all_emb
        spmm_gather_kernel<<<gather_blocks, 256, 0, stream>>>(
            (const float4*)all_emb, (const unsigned long long*)edata, Pstart,
            (float4*)x1, 0);
        // out = fc(all_emb) + x1
        fc_add_kernel<<<N_NODES / 4, 256, 0, stream>>>(all_emb, W, b, x1, out);
        // layer 1 (fused /3): out = (out + A2 @ x1) / 3
        spmm_gather_kernel<<<gather_blocks, 256, 0, stream>>>(
            (const float4*)x1, (const unsigned long long*)edata, Pstart,
            (float4*)out, 1);
    } else {
        // fallback: proven atomic path
        const int spmm_blocks = (N_EDGES + 3) / 4;
        zero_kernel<<<zb, 256, 0, stream>>>((float4*)x1, n4);
        spmm_atomic_kernel<<<spmm_blocks, 256, 0, stream>>>(all_emb, vals, drop_u,
                                                            rows, cols, x1);
        fc_add_kernel<<<N_NODES / 4, 256, 0, stream>>>(all_emb, W, b, x1, out);
        spmm_atomic_kernel<<<spmm_blocks, 256, 0, stream>>>(x1, vals,
                                                            drop_u + N_EDGES,
                                                            rows, cols, out);
        scale_kernel<<<zb, 256, 0, stream>>>((float4*)out, n4);
    }
}

// Round 7
// 376.870 us; speedup vs baseline: 1.2777x; 1.0068x over previous
//
#include <hip/hip_runtime.h>

#define N_NODES 100000
#define N_EDGES 1200000
#define D 64
#define KEEP_PROB 0.7f
#define INV_KEEP (1.0f / KEEP_PROB)
#define NB_SCAN 196   // ceil(N_NODES/512)

#define ALOAD_I(p)   __hip_atomic_load((p), __ATOMIC_RELAXED, __HIP_MEMORY_SCOPE_AGENT)
#define ALOAD_U64(p) __hip_atomic_load((p), __ATOMIC_RELAXED, __HIP_MEMORY_SCOPE_AGENT)

// ---------------------------------------------------------------------------
__global__ __launch_bounds__(256) void zero_kernel(float4* __restrict__ p, int n4) {
    int i = blockIdx.x * 256 + threadIdx.x;
    if (i < n4) p[i] = make_float4(0.f, 0.f, 0.f, 0.f);
}

// ---------------------------------------------------------------------------
// CSR build 1: per-row counts, 4 edges/thread (int4 loads, 4 indep atomics)
__global__ __launch_bounds__(256) void hist_kernel(const int4* __restrict__ rows4,
                                                   int* __restrict__ cnt) {
    int i = blockIdx.x * 256 + threadIdx.x;
    if (i >= N_EDGES / 4) return;
    int4 r = rows4[i];
    atomicAdd(&cnt[r.x], 1);
    atomicAdd(&cnt[r.y], 1);
    atomicAdd(&cnt[r.z], 1);
    atomicAdd(&cnt[r.w], 1);
}

// ---------------------------------------------------------------------------
// CSR build 2a: per-512-chunk sums of cnt
__global__ __launch_bounds__(256) void blocksum_kernel(const int* __restrict__ cnt,
                                                       int* __restrict__ bsum) {
    __shared__ int red[256];
    int t = threadIdx.x;
    int base = blockIdx.x * 512;
    int i0 = base + t, i1 = base + 256 + t;
    int s = 0;
    if (i0 < N_NODES) s += ALOAD_I(&cnt[i0]);
    if (i1 < N_NODES) s += ALOAD_I(&cnt[i1]);
    red[t] = s;
    __syncthreads();
    for (int d = 128; d > 0; d >>= 1) {
        if (t < d) red[t] += red[t + d];
        __syncthreads();
    }
    if (t == 0) bsum[blockIdx.x] = red[0];
}

// ---------------------------------------------------------------------------
// CSR build 2b: exclusive scan of 196 block sums (in place); sentinel
__global__ __launch_bounds__(256) void bscan_kernel(int* __restrict__ bsum,
                                                    int* __restrict__ Pstart) {
    __shared__ int part[256];
    int t = threadIdx.x;
    int v = (t < NB_SCAN) ? bsum[t] : 0;
    part[t] = v;
    __syncthreads();
    for (int d = 1; d < 256; d <<= 1) {
        int w = (t >= d) ? part[t - d] : 0;
        __syncthreads();
        part[t] += w;
        __syncthreads();
    }
    if (t < NB_SCAN) bsum[t] = part[t] - v;
    if (t == 0) Pstart[N_NODES] = N_EDGES;
}

// ---------------------------------------------------------------------------
// CSR build 2c: block-local exclusive scan + block offset -> Pstart, cursor
__global__ __launch_bounds__(256) void scan2_kernel(const int* __restrict__ cnt,
                                                    const int* __restrict__ bofs,
                                                    int* __restrict__ Pstart,
                                                    int* __restrict__ cursor) {
    __shared__ int part[256];
    int t = threadIdx.x;
    int base = blockIdx.x * 512;
    int i0 = base + 2 * t, i1 = i0 + 1;
    int e0 = (i0 < N_NODES) ? ALOAD_I(&cnt[i0]) : 0;
    int e1 = (i1 < N_NODES) ? ALOAD_I(&cnt[i1]) : 0;
    int s = e0 + e1;
    part[t] = s;
    __syncthreads();
    for (int d = 1; d < 256; d <<= 1) {
        int w = (t >= d) ? part[t - d] : 0;
        __syncthreads();
        part[t] += w;
        __syncthreads();
    }
    int pref = bofs[blockIdx.x] + part[t] - s;
    if (i0 < N_NODES) { Pstart[i0] = pref;      cursor[i0] = pref; }
    if (i1 < N_NODES) { Pstart[i1] = pref + e0; cursor[i1] = pref + e0; }
}

// ---------------------------------------------------------------------------
// CSR build 3: scatter, 4 edges/thread (vector input loads, 4 independent
// atomic->store chains for MLP). One 16B record per edge: (col,v0,col,v1).
__global__ __launch_bounds__(256) void scatter_kernel(
    const int4*   __restrict__ rows4,
    const int4*   __restrict__ cols4,
    const float4* __restrict__ vals4,
    const float4* __restrict__ u04,     // drop_u layer 0
    const float4* __restrict__ u14,     // drop_u layer 1
    int*          __restrict__ cursor,
    uint4*        __restrict__ edata) {
    int i = blockIdx.x * 256 + threadIdx.x;
    if (i >= N_EDGES / 4) return;
    int4   r  = rows4[i];
    int4   c  = cols4[i];
    float4 v  = vals4[i];
    float4 u0 = u04[i];
    float4 u1 = u14[i];

    int p0 = atomicAdd(&cursor[r.x], 1);
    int p1 = atomicAdd(&cursor[r.y], 1);
    int p2 = atomicAdd(&cursor[r.z], 1);
    int p3 = atomicAdd(&cursor[r.w], 1);

    uint4 rec;
    float vv;
    vv = v.x * INV_KEEP;
    rec.x = (unsigned)c.x; rec.z = (unsigned)c.x;
    rec.y = __float_as_uint((u0.x + KEEP_PROB >= 1.0f) ? vv : 0.f);
    rec.w = __float_as_uint((u1.x + KEEP_PROB >= 1.0f) ? vv : 0.f);
    edata[p0] = rec;
    vv = v.y * INV_KEEP;
    rec.x = (unsigned)c.y; rec.z = (unsigned)c.y;
    rec.y = __float_as_uint((u0.y + KEEP_PROB >= 1.0f) ? vv : 0.f);
    rec.w = __float_as_uint((u1.y + KEEP_PROB >= 1.0f) ? vv : 0.f);
    edata[p1] = rec;
    vv = v.z * INV_KEEP;
    rec.x = (unsigned)c.z; rec.z = (unsigned)c.z;
    rec.y = __float_as_uint((u0.z + KEEP_PROB >= 1.0f) ? vv : 0.f);
    rec.w = __float_as_uint((u1.z + KEEP_PROB >= 1.0f) ? vv : 0.f);
    edata[p2] = rec;
    vv = v.w * INV_KEEP;
    rec.x = (unsigned)c.w; rec.z = (unsigned)c.w;
    rec.y = __float_as_uint((u0.w + KEEP_PROB >= 1.0f) ? vv : 0.f);
    rec.w = __float_as_uint((u1.w + KEEP_PROB >= 1.0f) ? vv : 0.f);
    edata[p3] = rec;
}

// ---------------------------------------------------------------------------
// Gather SpMM: 16 lanes/row (float4/lane), 4 rows/wave, unroll 8.
// Dropped edges (v==0) remap their gather to row 0 (always L2-hot) --
// branch-free cndmask keeps the unrolled loads batched.
// layer 0: io[row] = acc ; layer 1: io[row] = (io[row] + acc) / 3
__global__ __launch_bounds__(256) void spmm_gather_kernel(
    const float4* __restrict__ x_in,
    const unsigned long long* __restrict__ edata,  // 2 u64 per edge
    const int*   __restrict__ Pstart,
    float4*      __restrict__ io,
    int layer) {
    int tid = blockIdx.x * 256 + threadIdx.x;
    int row = tid >> 4;
    int l16 = threadIdx.x & 15;
    if (row >= N_NODES) return;
    int start = ALOAD_I(&Pstart[row]);
    int end   = ALOAD_I(&Pstart[row + 1]);
    float4 acc = make_float4(0.f, 0.f, 0.f, 0.f);
    #pragma unroll 8
    for (int i = start; i < end; ++i) {
        unsigned long long rec = ALOAD_U64(&edata[2 * i + layer]);
        int   c = (int)(rec & 0xffffffffu);
        float v = __uint_as_float((unsigned)(rec >> 32));
        int  cc = (v != 0.f) ? c : 0;          // dropped -> hot row 0
        float4 x = x_in[(cc << 4) + l16];
        acc.x = fmaf(v, x.x, acc.x);
        acc.y = fmaf(v, x.y, acc.y);
        acc.z = fmaf(v, x.z, acc.z);
        acc.w = fmaf(v, x.w, acc.w);
    }
    int o = (row << 4) + l16;
    if (layer == 0) {
        io[o] = acc;
    } else {
        float4 p = io[o];
        p.x = (p.x + acc.x) * (1.0f / 3.0f);
        p.y = (p.y + acc.y) * (1.0f / 3.0f);
        p.z = (p.z + acc.z) * (1.0f / 3.0f);
        p.w = (p.w + acc.w) * (1.0f / 3.0f);
        io[o] = p;
    }
}

// ---------------------------------------------------------------------------
// out[n,j] = b[j] + sum_k emb[n,k]*W[j,k] + x1[n,j]
__global__ __launch_bounds__(256) void fc_add_kernel(
    const float* __restrict__ emb,
    const float* __restrict__ W,
    const float* __restrict__ b,
    const float* __restrict__ x1,
    float*       __restrict__ out) {
    __shared__ float Ws[D * 65];
    __shared__ float Es[4 * D];

    int t = threadIdx.x;
    #pragma unroll
    for (int i = 0; i < 16; ++i) {
        int idx = i * 256 + t;
        Ws[(idx >> 6) * 65 + (idx & 63)] = W[idx];
    }
    int node0 = blockIdx.x * 4;
    Es[t] = emb[node0 * D + t];
    __syncthreads();

    int local = t >> 6;
    int j     = t & 63;
    int n     = node0 + local;

    float acc = b[j];
    const float* es = &Es[local * D];
    const float* ws = &Ws[j * 65];
    #pragma unroll
    for (int k = 0; k < D; ++k) acc += es[k] * ws[k];
    out[n * D + j] = acc + x1[n * D + j];
}

// ---------------------------------------------------------------------------
// Fallback (atomic path, replay-proven) if ws too small
__global__ __launch_bounds__(256) void spmm_atomic_kernel(
    const float* __restrict__ x_in,
    const float* __restrict__ vals,
    const float* __restrict__ drop_u,
    const int*   __restrict__ rows,
    const int*   __restrict__ cols,
    float*       __restrict__ x_out) {
    int wave = (blockIdx.x * 256 + threadIdx.x) >> 6;
    int lane = threadIdx.x & 63;
    if (wave >= N_EDGES) return;
    float u = drop_u[wave];
    if (u + KEEP_PROB < 1.0f) return;
    float v = vals[wave] * INV_KEEP;
    atomicAdd(&x_out[rows[wave] * D + lane], v * x_in[cols[wave] * D + lane]);
}

__global__ __launch_bounds__(256) void scale_kernel(float4* __restrict__ p, int n4) {
    int i = blockIdx.x * 256 + threadIdx.x;
    if (i < n4) {
        float4 v = p[i];
        v.x *= (1.f/3.f); v.y *= (1.f/3.f); v.z *= (1.f/3.f); v.w *= (1.f/3.f);
        p[i] = v;
    }
}

// ---------------------------------------------------------------------------
extern "C" void kernel_launch(void* const* d_in, const int* in_sizes, int n_in,
                              void* d_out, int out_size, void* d_ws, size_t ws_size,
                              hipStream_t stream) {
    const float* all_emb = (const float*)d_in[0];
    const float* W       = (const float*)d_in[1];
    const float* b       = (const float*)d_in[2];
    const float* vals    = (const float*)d_in[3];
    const float* drop_u  = (const float*)d_in[4];   // [2, E]
    const int*   rows    = (const int*)d_in[5];
    const int*   cols    = (const int*)d_in[6];

    float* out = (float*)d_out;

    // workspace layout (16B aligned)
    char* ws = (char*)d_ws;
    float* x1     = (float*)(ws);                   // 25,600,000 B
    int*   Pstart = (int*)  (ws + 25600000);        //    400,064 B
    int*   cnt    = (int*)  (ws + 26000064);        //    400,000 B (counts -> cursor)
    uint4* edata  = (uint4*)(ws + 26400064);        // 19,200,000 B (E x 16B)
    int*   bsum   = (int*)  (ws + 45600064);        //      1,024 B
    const size_t WS_NEEDED = 45601088;

    const int n4 = N_NODES * D / 4;
    const int zb = (n4 + 255) / 256;
    const int e4_blocks = (N_EDGES / 4 + 255) / 256;      // 1172
    const int gather_blocks = (N_NODES * 16 + 255) / 256; // 6250

    if (ws_size >= WS_NEEDED) {
        zero_kernel<<<(N_NODES/4 + 255)/256, 256, 0, stream>>>((float4*)cnt, N_NODES/4);
        hist_kernel<<<e4_blocks, 256, 0, stream>>>((const int4*)rows, cnt);
        blocksum_kernel<<<NB_SCAN, 256, 0, stream>>>(cnt, bsum);
        bscan_kernel<<<1, 256, 0, stream>>>(bsum, Pstart);
        scan2_kernel<<<NB_SCAN, 256, 0, stream>>>(cnt, bsum, Pstart, cnt);
        scatter_kernel<<<e4_blocks, 256, 0, stream>>>(
            (const int4*)rows, (const int4*)cols, (const float4*)vals,
            (const float4*)drop_u, (const float4*)(drop_u + N_EDGES),
            cnt, edata);
        // layer 0: x1 = A1 @ all_emb
        spmm_gather_kernel<<<gather_blocks, 256, 0, stream>>>(
            (const float4*)all_emb, (const unsigned long long*)edata, Pstart,
            (float4*)x1, 0);
        // out = fc(all_emb) + x1
        fc_add_kernel<<<N_NODES / 4, 256, 0, stream>>>(all_emb, W, b, x1, out);
        // layer 1 (fused /3): out = (out + A2 @ x1) / 3
        spmm_gather_kernel<<<gather_blocks, 256, 0, stream>>>(
            (const float4*)x1, (const unsigned long long*)edata, Pstart,
            (float4*)out, 1);
    } else {
        // fallback: proven atomic path
        const int spmm_blocks = (N_EDGES + 3) / 4;
        zero_kernel<<<zb, 256, 0, stream>>>((float4*)x1, n4);
        spmm_atomic_kernel<<<spmm_blocks, 256, 0, stream>>>(all_emb, vals, drop_u,
                                                            rows, cols, x1);
        fc_add_kernel<<<N_NODES / 4, 256, 0, stream>>>(all_emb, W, b, x1, out);
        spmm_atomic_kernel<<<spmm_blocks, 256, 0, stream>>>(x1, vals,
                                                            drop_u + N_EDGES,
                                                            rows, cols, out);
        scale_kernel<<<zb, 256, 0, stream>>>((float4*)out, n4);
    }
}